// Round 1
// 1161.140 us; speedup vs baseline: 1.0161x; 1.0161x over previous
//
#include <hip/hip_runtime.h>

// Time2Vec: out[r][0:1024]   = w*x[r][:] + p                  (linear half)
//           out[r][1024:2048]= sw*sin(z)+cw*cos(z), z = xW+P  (periodic half)
//
// GEMM = split-bf16 3-term (Xhi*Whi + Xhi*Wlo + Xlo*Whi), K'=3072.
// This version: 256x256 tile, BK=32, 8 waves, phase-interleaved schedule with
// 4 LDS buffers, counted vmcnt(8) (never drained in-loop), T2 XOR swizzle
// (pre-swizzled global source + swizzled ds_read), T5 setprio, XCD swizzle.

typedef __attribute__((ext_vector_type(4))) float    f32x4;
typedef __attribute__((ext_vector_type(8))) short    short8;
typedef __attribute__((ext_vector_type(4))) unsigned short u16x4;

#define IN_F   1024
#define BATCH  65536

// ---- bf16 helpers (RNE, bit-level; inputs are finite normals) ----
__device__ __forceinline__ unsigned short f2bf(float f) {
    unsigned u = __float_as_uint(f);
    u += 0x7fffu + ((u >> 16) & 1u);
    return (unsigned short)(u >> 16);
}
__device__ __forceinline__ float bf2f(unsigned short b) {
    return __uint_as_float(((unsigned)b) << 16);
}

// ---- async global->LDS, 16B per lane (wave-uniform LDS base + lane*16) ----
__device__ __forceinline__ void async_copy16(const void* g, void* l) {
    __builtin_amdgcn_global_load_lds(
        (const __attribute__((address_space(1))) void*)g,
        (__attribute__((address_space(3))) void*)l, 16, 0, 0);
}

// ============================================================
// Prep 1: read x, write linear half of out, write x_hi/x_lo bf16
// ============================================================
__global__ __launch_bounds__(256) void prep_x_kernel(
    const f32x4* __restrict__ x4, const float* __restrict__ wp,
    const float* __restrict__ pp, float* __restrict__ out,
    u16x4* __restrict__ Xhi, u16x4* __restrict__ Xlo)
{
    unsigned idx = blockIdx.x * 256u + threadIdx.x;   // 0 .. 16777215
    f32x4 v = x4[idx];
    float w = wp[0], p = pp[0];
    unsigned e = idx * 4u;
    unsigned r = e >> 10, cc = e & 1023u;
    f32x4 o = v * w + p;
    *(f32x4*)(out + (size_t)r * 2048 + cc) = o;
    u16x4 h, l;
#pragma unroll
    for (int i = 0; i < 4; ++i) {
        unsigned short hh = f2bf(v[i]);
        h[i] = hh;
        l[i] = f2bf(v[i] - bf2f(hh));
    }
    Xhi[idx] = h;
    Xlo[idx] = l;
}

// ============================================================
// Prep 2: W[k][n] fp32 -> Whi_t[n][k], Wlo_t[n][k] bf16 (transpose + split)
// ============================================================
__global__ __launch_bounds__(256) void prep_w_kernel(
    const float* __restrict__ W,
    unsigned short* __restrict__ Whi, unsigned short* __restrict__ Wlo)
{
    __shared__ float t[32][33];
    int tx = threadIdx.x, ty = threadIdx.y;
    int n0 = blockIdx.x * 32, k0 = blockIdx.y * 32;
#pragma unroll
    for (int i = 0; i < 4; ++i)
        t[ty + i * 8][tx] = W[(size_t)(k0 + ty + i * 8) * IN_F + n0 + tx];
    __syncthreads();
#pragma unroll
    for (int i = 0; i < 4; ++i) {
        float v = t[tx][ty + i * 8];
        int n = n0 + ty + i * 8, k = k0 + tx;
        unsigned short h = f2bf(v);
        Whi[(size_t)n * IN_F + k] = h;
        Wlo[(size_t)n * IN_F + k] = f2bf(v - bf2f(h));
    }
}

// ============================================================
// GEMM: 256x256 tile, BK=32, 512 thr (8 waves 2x4), phase-interleaved,
// 4-deep LDS tile pipeline, counted vmcnt, XOR-swizzled LDS.
// K' = 3072 = 96 K-tiles; part = kt>>5 selects {Xhi*Whi, Xhi*Wlo, Xlo*Whi}.
// ============================================================
__global__ __launch_bounds__(512, 2) void gemm_kernel(
    const unsigned short* __restrict__ Xhi, const unsigned short* __restrict__ Xlo,
    const unsigned short* __restrict__ Whi, const unsigned short* __restrict__ Wlo,
    const float* __restrict__ P, const float* __restrict__ swp,
    const float* __restrict__ cwp, float* __restrict__ out)
{
    // 4 buffers x (A: 256x32 bf16 = 16KB) and same for B -> 128 KiB total
    __shared__ __align__(16) char As[65536];
    __shared__ __align__(16) char Bs[65536];

    const int tid  = threadIdx.x;
    const int lane = tid & 63;
    const int wave = tid >> 6;
    const int wm   = wave >> 2;      // 0..1  -> 128-row half
    const int wn   = wave & 3;       // 0..3  -> 64-col quarter

    // XCD-bijective swizzle: 1024 wgs, each XCD gets 32 contiguous m-bands
    // (with all 4 n-blocks) -> A-panel reuse inside one XCD's L2.
    int bid = blockIdx.x;                       // 0..1023
    int wg  = (bid & 7) * 128 + (bid >> 3);
    const int m0 = (wg >> 2) * 256;
    const int n0 = (wg & 3) * 256;

    // ---- read-side constants (T2 swizzle folds to a per-thread constant) ----
    // frag: row = base + (lane&15), k-slot = lane>>4 ; LDS slot' = slot ^ f(row)
    const int fr    = lane & 15;
    const int fsw   = (fr ^ (fr >> 2)) & 3;
    const int slotp = (lane >> 4) ^ fsw;
    const unsigned aoff = (unsigned)((wm * 128 + fr) * 64 + slotp * 16);
    const unsigned boff = (unsigned)((wn * 64 + fr) * 64 + slotp * 16);

    // ---- stage-side constants: LDS dest is linear (tid*16), global source
    // column is inverse-swizzled with the same involution.
    const int srow  = tid >> 2;                                   // 0..127
    const int sslot = (tid & 3) ^ (((tid >> 2) ^ (tid >> 4)) & 3);
    const size_t aRow0 = (size_t)(m0 + srow) * IN_F + sslot * 8;
    const size_t aRow1 = (size_t)(m0 + 128 + srow) * IN_F + sslot * 8;
    const size_t bRow0 = (size_t)(n0 + srow) * IN_F + sslot * 8;
    const size_t bRow1 = (size_t)(n0 + 128 + srow) * IN_F + sslot * 8;
    const unsigned ldsW = (unsigned)(wave * 1024);

    f32x4 acc[8][4] = {};

    auto stageA = [&](int kt) {   // 2 x global_load_lds (16 KB tile)
        const unsigned short* Ap = ((kt >> 5) == 2) ? Xlo : Xhi;
        int k0e = (kt & 31) * 32;
        char* d = As + (kt & 3) * 16384 + ldsW;
        async_copy16(Ap + aRow0 + k0e, d);
        async_copy16(Ap + aRow1 + k0e, d + 8192);
    };
    auto stageB = [&](int kt) {
        const unsigned short* Bp = ((kt >> 5) == 1) ? Wlo : Whi;
        int k0e = (kt & 31) * 32;
        char* d = Bs + (kt & 3) * 16384 + ldsW;
        async_copy16(Bp + bRow0 + k0e, d);
        async_copy16(Bp + bRow1 + k0e, d + 8192);
    };

    // prologue: stage tiles 0,1,2 (12 loads/thread), wait oldest 4 (= tile 0)
    stageA(0); stageB(0);
    stageA(1); stageB(1);
    stageA(2); stageB(2);
    asm volatile("s_waitcnt vmcnt(8)" ::: "memory");
    __builtin_amdgcn_s_barrier();

    for (int t = 0; t < 96; ++t) {
        const char* aBase = As + (t & 3) * 16384 + aoff;
        const char* bBase = Bs + (t & 3) * 16384 + boff;
        short8 av[4], bv[4], av2[4];

        // ---- phase 0: read B + A-half0, issue A(t+3), 16 MFMA ----
#pragma unroll
        for (int i = 0; i < 4; ++i) av[i] = *(const short8*)(aBase + i * 1024);
#pragma unroll
        for (int j = 0; j < 4; ++j) bv[j] = *(const short8*)(bBase + j * 1024);
        if (t + 3 < 96) stageA(t + 3);
        __builtin_amdgcn_s_barrier();
        __builtin_amdgcn_s_setprio(1);
#pragma unroll
        for (int i = 0; i < 4; ++i)
#pragma unroll
            for (int j = 0; j < 4; ++j)
                acc[i][j] = __builtin_amdgcn_mfma_f32_16x16x32_bf16(
                    av[i], bv[j], acc[i][j], 0, 0, 0);
        __builtin_amdgcn_s_setprio(0);
        __builtin_amdgcn_s_barrier();

        // ---- phase 1: read A-half1, issue B(t+3), counted vmcnt, 16 MFMA ----
#pragma unroll
        for (int i = 0; i < 4; ++i) av2[i] = *(const short8*)(aBase + 4096 + i * 1024);
        if (t + 3 < 96) stageB(t + 3);
        __builtin_amdgcn_s_barrier();
        __builtin_amdgcn_s_setprio(1);
#pragma unroll
        for (int i = 0; i < 4; ++i)
#pragma unroll
            for (int j = 0; j < 4; ++j)
                acc[4 + i][j] = __builtin_amdgcn_mfma_f32_16x16x32_bf16(
                    av2[i], bv[j], acc[4 + i][j], 0, 0, 0);
        __builtin_amdgcn_s_setprio(0);
        // guarantee tile t+1 fully landed before any wave reads it next iter:
        // issued = 4(t+4), needed = 4(t+2)  ->  vmcnt(8). Tail drains.
        if (t < 93) { asm volatile("s_waitcnt vmcnt(8)" ::: "memory"); }
        else        { asm volatile("s_waitcnt vmcnt(0)" ::: "memory"); }
        __builtin_amdgcn_s_barrier();
    }

    // ---- epilogue: z = acc + P[col]; out_periodic = sw*sin(z)+cw*cos(z) ----
    const float sw = swp[0], cw = cwp[0];
#pragma unroll
    for (int j = 0; j < 4; ++j) {
        const int colg = n0 + wn * 64 + j * 16 + fr;
        const float pcol = P[colg];
#pragma unroll
        for (int i = 0; i < 8; ++i) {
#pragma unroll
            for (int r = 0; r < 4; ++r) {
                int rowg = m0 + wm * 128 + i * 16 + (lane >> 4) * 4 + r;
                float z = acc[i][j][r] + pcol;
                float val = sw * __sinf(z) + cw * __cosf(z);
                out[(size_t)rowg * 2048 + 1024 + colg] = val;
            }
        }
    }
}

// ============================================================
// Fallback (only if workspace too small): naive but correct
// ============================================================
__global__ __launch_bounds__(256) void naive_kernel(
    const float* __restrict__ x, const float* __restrict__ W,
    const float* __restrict__ P, const float* __restrict__ wp,
    const float* __restrict__ pp, const float* __restrict__ swp,
    const float* __restrict__ cwp, float* __restrict__ out)
{
    size_t idx = (size_t)blockIdx.x * 256 + threadIdx.x;
    if (idx >= (size_t)BATCH * IN_F) return;
    size_t r = idx >> 10;
    int n = (int)(idx & 1023);
    float acc = 0.f;
    for (int k = 0; k < IN_F; ++k)
        acc = fmaf(x[r * IN_F + k], W[(size_t)k * IN_F + n], acc);
    float z = acc + P[n];
    out[r * 2048 + n] = wp[0] * x[r * IN_F + n] + pp[0];
    out[r * 2048 + 1024 + n] = swp[0] * __sinf(z) + cwp[0] * __cosf(z);
}

extern "C" void kernel_launch(void* const* d_in, const int* in_sizes, int n_in,
                              void* d_out, int out_size, void* d_ws, size_t ws_size,
                              hipStream_t stream)
{
    const float* x   = (const float*)d_in[0];
    const float* W   = (const float*)d_in[1];
    const float* P   = (const float*)d_in[2];
    const float* w   = (const float*)d_in[3];
    const float* p   = (const float*)d_in[4];
    const float* swv = (const float*)d_in[5];
    const float* cwv = (const float*)d_in[6];
    float* out = (float*)d_out;

    const size_t xElems = (size_t)BATCH * IN_F;          // 67,108,864
    const size_t wElems = (size_t)IN_F * IN_F;           // 1,048,576
    const size_t need   = xElems * 2 * 2 + wElems * 2 * 2;  // ~260 MB

    if (ws_size >= need) {
        unsigned short* Xhi = (unsigned short*)d_ws;
        unsigned short* Xlo = Xhi + xElems;
        unsigned short* Whi = Xlo + xElems;
        unsigned short* Wlo = Whi + wElems;

        prep_x_kernel<<<65536, 256, 0, stream>>>(
            (const f32x4*)x, w, p, out, (u16x4*)Xhi, (u16x4*)Xlo);
        prep_w_kernel<<<dim3(32, 32), dim3(32, 8), 0, stream>>>(W, Whi, Wlo);
        gemm_kernel<<<1024, 512, 0, stream>>>(Xhi, Xlo, Whi, Wlo, P, swv, cwv, out);
    } else {
        naive_kernel<<<(unsigned)((xElems + 255) / 256), 256, 0, stream>>>(
            x, W, P, w, p, swv, cwv, out);
    }
}

// Round 2
// 1129.369 us; speedup vs baseline: 1.0447x; 1.0281x over previous
//
#include <hip/hip_runtime.h>

// Time2Vec: out[r][0:1024]   = w*x[r][:] + p                  (linear half)
//           out[r][1024:2048]= sw*sin(z)+cw*cos(z), z = xW+P  (periodic half)
//
// GEMM = split-bf16 3-term (Xhi*Whi + Xhi*Wlo + Xlo*Whi), K'=3072.
// This version: 256x256 tile, BK=32, 8 waves, 32x32x16 MFMA, AITER-style
// pipelined K-loop: reg double-buffered fragments, 1 barrier + 1 counted
// vmcnt(4) per K-tile (never drained mid-loop), 4-deep LDS, T2 swizzle,
// T5 setprio, XCD swizzle. prep_x is now grid-stride (2048 blocks).

typedef __attribute__((ext_vector_type(4)))  float    f32x4;
typedef __attribute__((ext_vector_type(16))) float    f32x16;
typedef __attribute__((ext_vector_type(8)))  short    short8;
typedef __attribute__((ext_vector_type(4)))  unsigned short u16x4;

#define IN_F   1024
#define BATCH  65536

// ---- bf16 helpers (RNE, bit-level; inputs are finite normals) ----
__device__ __forceinline__ unsigned short f2bf(float f) {
    unsigned u = __float_as_uint(f);
    u += 0x7fffu + ((u >> 16) & 1u);
    return (unsigned short)(u >> 16);
}
__device__ __forceinline__ float bf2f(unsigned short b) {
    return __uint_as_float(((unsigned)b) << 16);
}

// ---- async global->LDS, 16B per lane (wave-uniform LDS base + lane*16) ----
__device__ __forceinline__ void async_copy16(const void* g, void* l) {
    __builtin_amdgcn_global_load_lds(
        (const __attribute__((address_space(1))) void*)g,
        (__attribute__((address_space(3))) void*)l, 16, 0, 0);
}

// ============================================================
// Prep 1: grid-stride (2048 blocks): read x, write linear half of out,
// write x_hi/x_lo bf16 split.
// ============================================================
__global__ __launch_bounds__(256) void prep_x_kernel(
    const f32x4* __restrict__ x4, const float* __restrict__ wp,
    const float* __restrict__ pp, float* __restrict__ out,
    u16x4* __restrict__ Xhi, u16x4* __restrict__ Xlo)
{
    const float w = wp[0], p = pp[0];
    for (unsigned idx = blockIdx.x * 256u + threadIdx.x; idx < 16777216u;
         idx += 2048u * 256u) {
        f32x4 v = x4[idx];
        unsigned e = idx * 4u;
        unsigned r = e >> 10, cc = e & 1023u;
        f32x4 o = v * w + p;
        *(f32x4*)(out + (size_t)r * 2048 + cc) = o;
        u16x4 h, l;
#pragma unroll
        for (int i = 0; i < 4; ++i) {
            unsigned short hh = f2bf(v[i]);
            h[i] = hh;
            l[i] = f2bf(v[i] - bf2f(hh));
        }
        Xhi[idx] = h;
        Xlo[idx] = l;
    }
}

// ============================================================
// Prep 2: W[k][n] fp32 -> Whi_t[n][k], Wlo_t[n][k] bf16 (transpose + split)
// ============================================================
__global__ __launch_bounds__(256) void prep_w_kernel(
    const float* __restrict__ W,
    unsigned short* __restrict__ Whi, unsigned short* __restrict__ Wlo)
{
    __shared__ float t[32][33];
    int tx = threadIdx.x, ty = threadIdx.y;
    int n0 = blockIdx.x * 32, k0 = blockIdx.y * 32;
#pragma unroll
    for (int i = 0; i < 4; ++i)
        t[ty + i * 8][tx] = W[(size_t)(k0 + ty + i * 8) * IN_F + n0 + tx];
    __syncthreads();
#pragma unroll
    for (int i = 0; i < 4; ++i) {
        float v = t[tx][ty + i * 8];
        int n = n0 + ty + i * 8, k = k0 + tx;
        unsigned short h = f2bf(v);
        Whi[(size_t)n * IN_F + k] = h;
        Wlo[(size_t)n * IN_F + k] = f2bf(v - bf2f(h));
    }
}

// ============================================================
// GEMM kernel
// ============================================================

// ds_read one tile's fragments into (A_, B_). A: 4 m-frags x 2 k-steps,
// B: 2 n-frags x 2 k-steps. ks=1 address = ks=0 address ^ 32 (swizzle).
#define READS(tt, A_, B_) do {                                               \
    const char* aT_ = As + ((tt) & 3) * 16384;                               \
    const char* bT_ = Bs + ((tt) & 3) * 16384;                               \
    A_[0] = *(const short8*)(aT_ + aO0);        A_[1] = *(const short8*)(aT_ + aO1);        \
    A_[2] = *(const short8*)(aT_ + aO0 + 2048); A_[3] = *(const short8*)(aT_ + aO1 + 2048); \
    A_[4] = *(const short8*)(aT_ + aO0 + 4096); A_[5] = *(const short8*)(aT_ + aO1 + 4096); \
    A_[6] = *(const short8*)(aT_ + aO0 + 6144); A_[7] = *(const short8*)(aT_ + aO1 + 6144); \
    B_[0] = *(const short8*)(bT_ + bO0);        B_[1] = *(const short8*)(bT_ + bO1);        \
    B_[2] = *(const short8*)(bT_ + bO0 + 2048); B_[3] = *(const short8*)(bT_ + bO1 + 2048); \
} while (0)

// 16 MFMA on (A_, B_): ks=0 wave (8 independent), then ks=1 wave.
#define MFMAS(A_, B_) do {                                                   \
    __builtin_amdgcn_s_setprio(1);                                           \
    _Pragma("unroll")                                                        \
    for (int mi_ = 0; mi_ < 4; ++mi_)                                        \
        _Pragma("unroll")                                                    \
        for (int nj_ = 0; nj_ < 2; ++nj_)                                    \
            acc[mi_][nj_] = __builtin_amdgcn_mfma_f32_32x32x16_bf16(         \
                A_[mi_ * 2 + 0], B_[nj_ * 2 + 0], acc[mi_][nj_], 0, 0, 0);   \
    _Pragma("unroll")                                                        \
    for (int mi_ = 0; mi_ < 4; ++mi_)                                        \
        _Pragma("unroll")                                                    \
        for (int nj_ = 0; nj_ < 2; ++nj_)                                    \
            acc[mi_][nj_] = __builtin_amdgcn_mfma_f32_32x32x16_bf16(         \
                A_[mi_ * 2 + 1], B_[nj_ * 2 + 1], acc[mi_][nj_], 0, 0, 0);   \
    __builtin_amdgcn_s_setprio(0);                                           \
} while (0)

__global__ __launch_bounds__(512, 2) void gemm_kernel(
    const unsigned short* __restrict__ Xhi, const unsigned short* __restrict__ Xlo,
    const unsigned short* __restrict__ Whi, const unsigned short* __restrict__ Wlo,
    const float* __restrict__ P, const float* __restrict__ swp,
    const float* __restrict__ cwp, float* __restrict__ out)
{
    // 4 buffers x (256 rows x 64B) for each of A,B -> 128 KiB
    __shared__ __align__(16) char As[65536];
    __shared__ __align__(16) char Bs[65536];

    const int tid  = threadIdx.x;
    const int lane = tid & 63;
    const int wave = tid >> 6;
    const int wm   = wave >> 2;      // 0..1  -> 128-row half
    const int wn   = wave & 3;       // 0..3  -> 64-col quarter

    // XCD-bijective swizzle: 1024 wgs, each XCD gets 32 contiguous m-bands.
    int bid = blockIdx.x;                       // 0..1023
    int wg  = (bid & 7) * 128 + (bid >> 3);
    const int m0 = (wg >> 2) * 256;
    const int n0 = (wg & 3) * 256;

    // ---- read-side constants (32x32 frags). row = base + (lane&31),
    // logical slot = ks*2 + (lane>>5); phys slot = logical ^ fsw(row) where
    // fsw(row) = (row ^ row>>2)&3 folds to a per-lane constant.
    const int rl  = lane & 31;
    const int kh  = lane >> 5;                       // 0/1
    const int fsw = (rl ^ (rl >> 2)) & 3;
    const int s0  = kh ^ fsw;
    const unsigned aO0 = (unsigned)((wm * 128 + rl) * 64 + s0 * 16);
    const unsigned aO1 = aO0 ^ 32u;                  // ks=1
    const unsigned bO0 = (unsigned)((wn * 64 + rl) * 64 + s0 * 16);
    const unsigned bO1 = bO0 ^ 32u;

    // ---- stage-side constants: LDS dest linear (tid*16); global source
    // column inverse-swizzled with the same involution.
    const int srow  = tid >> 2;                                   // 0..127
    const int sslot = (tid & 3) ^ (((tid >> 2) ^ (tid >> 4)) & 3);
    const size_t aRow0 = (size_t)(m0 + srow) * IN_F + sslot * 8;
    const size_t aRow1 = (size_t)(m0 + 128 + srow) * IN_F + sslot * 8;
    const size_t bRow0 = (size_t)(n0 + srow) * IN_F + sslot * 8;
    const size_t bRow1 = (size_t)(n0 + 128 + srow) * IN_F + sslot * 8;
    const unsigned ldsW = (unsigned)(wave * 1024);

    f32x16 acc[4][2] = {};

    auto stage = [&](int kt) {   // 4 x global_load_lds (one 32-KB A+B tile)
        const unsigned short* Ap = ((kt >> 5) == 2) ? Xlo : Xhi;
        const unsigned short* Bp = ((kt >> 5) == 1) ? Wlo : Whi;
        int k0e = (kt & 31) * 32;
        char* dA = As + (kt & 3) * 16384 + ldsW;
        char* dB = Bs + (kt & 3) * 16384 + ldsW;
        async_copy16(Ap + aRow0 + k0e, dA);
        async_copy16(Ap + aRow1 + k0e, dA + 8192);
        async_copy16(Bp + bRow0 + k0e, dB);
        async_copy16(Bp + bRow1 + k0e, dB + 8192);
    };

    // prologue: stage tiles 0,1,2; wait so 0,1 landed (tile 2 in flight)
    stage(0); stage(1); stage(2);
    asm volatile("s_waitcnt vmcnt(4)" ::: "memory");
    __builtin_amdgcn_s_barrier();

    short8 fA0[8], fB0[4], fA1[8], fB1[4];
    READS(0, fA0, fB0);

    // main loop: per K-tile = {reads(t+1) || MFMA(t)}, stage(t+3),
    // counted vmcnt(4), ONE barrier. Invariant entering t: frags(t) in regs,
    // stages (t),(t+1) landed, (t+2) in flight.
    for (int t = 0; t < 92; t += 2) {
        // even t: compute set0, fill set1
        READS(t + 1, fA1, fB1);
        stage(t + 3);
        MFMAS(fA0, fB0);
        asm volatile("s_waitcnt vmcnt(4)" ::: "memory");
        __builtin_amdgcn_s_barrier();
        // odd t+1: compute set1, fill set0
        READS(t + 2, fA0, fB0);
        stage(t + 4);
        MFMAS(fA1, fB1);
        asm volatile("s_waitcnt vmcnt(4)" ::: "memory");
        __builtin_amdgcn_s_barrier();
    }
    // tail: t = 92..95 (no more stages after 95)
    READS(93, fA1, fB1);
    stage(95);
    MFMAS(fA0, fB0);
    asm volatile("s_waitcnt vmcnt(4)" ::: "memory");
    __builtin_amdgcn_s_barrier();

    READS(94, fA0, fB0);
    MFMAS(fA1, fB1);
    asm volatile("s_waitcnt vmcnt(0)" ::: "memory");
    __builtin_amdgcn_s_barrier();

    READS(95, fA1, fB1);
    MFMAS(fA0, fB0);
    MFMAS(fA1, fB1);

    // ---- epilogue: z = acc + P[col]; out_periodic = sw*sin(z)+cw*cos(z) ----
    // C layout (32x32): col = lane&31, row = (reg&3) + 8*(reg>>2) + 4*(lane>>5)
    const float sw = swp[0], cw = cwp[0];
#pragma unroll
    for (int nj = 0; nj < 2; ++nj) {
        const int colg = n0 + wn * 64 + nj * 32 + rl;
        const float pcol = P[colg];
#pragma unroll
        for (int mi = 0; mi < 4; ++mi) {
#pragma unroll
            for (int r = 0; r < 16; ++r) {
                int rowg = m0 + wm * 128 + mi * 32 + (r & 3) + 8 * (r >> 2) + 4 * kh;
                float z = acc[mi][nj][r] + pcol;
                out[(size_t)rowg * 2048 + 1024 + colg] = sw * __sinf(z) + cw * __cosf(z);
            }
        }
    }
}

// ============================================================
// Fallback (only if workspace too small): naive but correct
// ============================================================
__global__ __launch_bounds__(256) void naive_kernel(
    const float* __restrict__ x, const float* __restrict__ W,
    const float* __restrict__ P, const float* __restrict__ wp,
    const float* __restrict__ pp, const float* __restrict__ swp,
    const float* __restrict__ cwp, float* __restrict__ out)
{
    size_t idx = (size_t)blockIdx.x * 256 + threadIdx.x;
    if (idx >= (size_t)BATCH * IN_F) return;
    size_t r = idx >> 10;
    int n = (int)(idx & 1023);
    float acc = 0.f;
    for (int k = 0; k < IN_F; ++k)
        acc = fmaf(x[r * IN_F + k], W[(size_t)k * IN_F + n], acc);
    float z = acc + P[n];
    out[r * 2048 + n] = wp[0] * x[r * IN_F + n] + pp[0];
    out[r * 2048 + 1024 + n] = swp[0] * __sinf(z) + cwp[0] * __cosf(z);
}

extern "C" void kernel_launch(void* const* d_in, const int* in_sizes, int n_in,
                              void* d_out, int out_size, void* d_ws, size_t ws_size,
                              hipStream_t stream)
{
    const float* x   = (const float*)d_in[0];
    const float* W   = (const float*)d_in[1];
    const float* P   = (const float*)d_in[2];
    const float* w   = (const float*)d_in[3];
    const float* p   = (const float*)d_in[4];
    const float* swv = (const float*)d_in[5];
    const float* cwv = (const float*)d_in[6];
    float* out = (float*)d_out;

    const size_t xElems = (size_t)BATCH * IN_F;          // 67,108,864
    const size_t wElems = (size_t)IN_F * IN_F;           // 1,048,576
    const size_t need   = xElems * 2 * 2 + wElems * 2 * 2;  // ~260 MB

    if (ws_size >= need) {
        unsigned short* Xhi = (unsigned short*)d_ws;
        unsigned short* Xlo = Xhi + xElems;
        unsigned short* Whi = Xlo + xElems;
        unsigned short* Wlo = Whi + wElems;

        prep_x_kernel<<<2048, 256, 0, stream>>>(
            (const f32x4*)x, w, p, out, (u16x4*)Xhi, (u16x4*)Xlo);
        prep_w_kernel<<<dim3(32, 32), dim3(32, 8), 0, stream>>>(W, Whi, Wlo);
        gemm_kernel<<<1024, 512, 0, stream>>>(Xhi, Xlo, Whi, Wlo, P, swv, cwv, out);
    } else {
        naive_kernel<<<(unsigned)((xElems + 255) / 256), 256, 0, stream>>>(
            x, W, P, w, p, swv, cwv, out);
    }
}